// Round 4
// baseline (14269.478 us; speedup 1.0000x reference)
//
#include <hip/hip_runtime.h>
#include <math.h>

// Problem constants
#define BB 64
#define SS 512
#define DD 256
#define HH 512
#define GG 1536   // 3H
#define SC 128    // steps per x_proj chunk
#define NCHUNK 4

// d_out scratch layout (float offsets) — d_out is dead until attn_fused rewrites it
#define OUT_OFF_WIHT 0UL
#define OUT_SZ_WIHT  (256UL * 1536UL)          // 393216
#define OUT_OFF_WHHT (OUT_OFF_WIHT + OUT_SZ_WIHT)
#define OUT_SZ_WHHT  (512UL * 1536UL)          // 786432
#define OUT_OFF_XC   (OUT_OFF_WHHT + OUT_SZ_WHHT)
#define OUT_SZ_XC    ((size_t)SC * BB * GG)    // 12582912 -> total 13762560 < 16777216

__device__ __forceinline__ float sigmoidf_(float x) {
  return 1.f / (1.f + expf(-x));
}

// ---------------- transpose: out[c][r] = in[r][c] ----------------
__global__ __launch_bounds__(256) void transpose_k(const float* __restrict__ in,
                                                   float* __restrict__ out,
                                                   int R, int C) {
  __shared__ float tile[32][33];
  int bx = blockIdx.x * 32;  // C base
  int by = blockIdx.y * 32;  // R base
  int tx = threadIdx.x, ty = threadIdx.y;  // 32 x 8
  for (int i = ty; i < 32; i += 8) {
    int r = by + i, c = bx + tx;
    if (r < R && c < C) tile[i][tx] = in[(size_t)r * C + c];
  }
  __syncthreads();
  for (int i = ty; i < 32; i += 8) {
    int c = bx + i, r = by + tx;
    if (c < C && r < R) out[(size_t)c * R + r] = tile[tx][i];
  }
}

// -------- x_proj chunk GEMM: xc[sl][b][g] = inp[b][s0+sl][:] . WihT[:][g] + b_ih[g]
// grid: (GG/64, SC); block 256. M-dim = 64 batches, K = 256.
__global__ __launch_bounds__(256) void xproj_gemm(const float* __restrict__ inp,
                                                  const float* __restrict__ WihT,
                                                  const float* __restrict__ b_ih,
                                                  float* __restrict__ xc, int s0) {
  const int sl = blockIdx.y;
  const int n0 = blockIdx.x * 64;
  const int srow = s0 + sl;
  const int tx = threadIdx.x & 15, ty = threadIdx.x >> 4;
  __shared__ float As[64][36];   // [batch][k] ; 36*4=144B rows (16B aligned)
  __shared__ float Bs[32][68];   // [k][g]
  float acc[4][4] = {};

  for (int k0 = 0; k0 < DD; k0 += 32) {
#pragma unroll
    for (int i = 0; i < 2; ++i) {  // stage A 64x32 (rows = batches)
      int f = threadIdx.x + 256 * i;
      int m = f >> 3, kq = (f & 7) << 2;
      *(float4*)&As[m][kq] =
          *(const float4*)&inp[((size_t)m * SS + srow) * DD + k0 + kq];
    }
#pragma unroll
    for (int i = 0; i < 2; ++i) {  // stage B 32x64
      int f = threadIdx.x + 256 * i;
      int n4 = (f & 15) << 2, kk = f >> 4;
      *(float4*)&Bs[kk][n4] =
          *(const float4*)&WihT[(size_t)(k0 + kk) * GG + n0 + n4];
    }
    __syncthreads();
#pragma unroll
    for (int kk = 0; kk < 32; ++kk) {
      float a[4];
#pragma unroll
      for (int i = 0; i < 4; ++i) a[i] = As[ty * 4 + i][kk];
      float4 b4 = *(const float4*)&Bs[kk][tx * 4];
      float bb[4] = {b4.x, b4.y, b4.z, b4.w};
#pragma unroll
      for (int i = 0; i < 4; ++i)
#pragma unroll
        for (int j = 0; j < 4; ++j) acc[i][j] = fmaf(a[i], bb[j], acc[i][j]);
    }
    __syncthreads();
  }
  const float g0 = b_ih[n0 + tx * 4 + 0], g1 = b_ih[n0 + tx * 4 + 1];
  const float g2 = b_ih[n0 + tx * 4 + 2], g3 = b_ih[n0 + tx * 4 + 3];
#pragma unroll
  for (int i = 0; i < 4; ++i) {
    int m = ty * 4 + i;  // batch
    float4 o = {acc[i][0] + g0, acc[i][1] + g1, acc[i][2] + g2, acc[i][3] + g3};
    *(float4*)&xc[((size_t)sl * BB + m) * GG + n0 + tx * 4] = o;
  }
}

// ---------------- GRU scan chunk: 1 WG per batch, thread j owns unit j -------
__global__ __launch_bounds__(512) void gru_scan_chunk(const float* __restrict__ xc,
                                                      const float* __restrict__ WhhT,
                                                      const float* __restrict__ b_hh,
                                                      float* __restrict__ h_all,
                                                      int s0) {
  const int b = blockIdx.x;
  const int j = threadIdx.x;  // 0..511
  __shared__ float hs[HH];
  hs[j] = (s0 == 0) ? 0.f : h_all[((size_t)b * SS + (s0 - 1)) * HH + j];
  __syncthreads();
  const float bh_r = b_hh[j], bh_z = b_hh[HH + j], bh_n = b_hh[2 * HH + j];
  float* hout = h_all + (size_t)b * SS * HH;

  for (int sl = 0; sl < SC; ++sl) {
    float ar = bh_r, az = bh_z, an = bh_n;
    const float* w = WhhT + j;
#pragma unroll 4
    for (int k = 0; k < HH; k += 4) {
      float4 h4 = *(const float4*)&hs[k];
      ar = fmaf(w[0], h4.x, ar); az = fmaf(w[HH], h4.x, az); an = fmaf(w[2 * HH], h4.x, an); w += GG;
      ar = fmaf(w[0], h4.y, ar); az = fmaf(w[HH], h4.y, az); an = fmaf(w[2 * HH], h4.y, an); w += GG;
      ar = fmaf(w[0], h4.z, ar); az = fmaf(w[HH], h4.z, az); an = fmaf(w[2 * HH], h4.z, an); w += GG;
      ar = fmaf(w[0], h4.w, ar); az = fmaf(w[HH], h4.w, az); an = fmaf(w[2 * HH], h4.w, an); w += GG;
    }
    const float* xp = xc + ((size_t)sl * BB + b) * GG;
    float r = sigmoidf_(xp[j] + ar);
    float z = sigmoidf_(xp[HH + j] + az);
    float n = tanhf(xp[2 * HH + j] + r * an);
    float hprev = hs[j];
    float hnew = (1.f - z) * n + z * hprev;
    __syncthreads();            // everyone done reading hs
    hs[j] = hnew;
    hout[(size_t)(s0 + sl) * HH + j] = hnew;
    __syncthreads();            // hnew visible
  }
}

// ------- fused attention: gram -> full-row softmax -> tril mask -> PV --------
// grid (SS/32, BB); block 256. 32 output rows per block; scores in LDS.
#define AR 32
__global__ __launch_bounds__(256) void attn_fused(const float* __restrict__ h_all,
                                                  float* __restrict__ out) {
  const int b = blockIdx.y;
  const int r0 = blockIdx.x * AR;
  const float* h = h_all + (size_t)b * SS * HH;  // [512][512]
  __shared__ float Ssc[AR][SS + 4];  // 32 x 516 scores (2064B rows, 16B aligned)
  __shared__ float Bt[32][68];
  __shared__ float At[AR][36];
  const int tx = threadIdx.x & 15, ty = threadIdx.x >> 4;  // ty: 2 rows each

  // ---- phase 1: Ssc = h[r0:r0+32] @ h^T  (M=32, N=512, K=512) ----
  for (int nt = 0; nt < 8; ++nt) {
    const int n0 = nt * 64;
    float acc[2][4] = {};
    for (int k0 = 0; k0 < HH; k0 += 32) {
      {  // stage At 32x32
        int m = threadIdx.x >> 3, kq = (threadIdx.x & 7) << 2;
        *(float4*)&At[m][kq] =
            *(const float4*)&h[(size_t)(r0 + m) * HH + k0 + kq];
      }
#pragma unroll
      for (int i = 0; i < 2; ++i) {  // stage Bt = h[n0+n][k0+kk] transposed
        int f = threadIdx.x + 256 * i;
        int n = f >> 3, kq = (f & 7) << 2;
        float4 bv = *(const float4*)&h[(size_t)(n0 + n) * HH + k0 + kq];
        Bt[kq + 0][n] = bv.x; Bt[kq + 1][n] = bv.y;
        Bt[kq + 2][n] = bv.z; Bt[kq + 3][n] = bv.w;
      }
      __syncthreads();
#pragma unroll
      for (int kk = 0; kk < 32; ++kk) {
        float a0 = At[ty * 2 + 0][kk], a1 = At[ty * 2 + 1][kk];
        float4 b4 = *(const float4*)&Bt[kk][tx * 4];
        acc[0][0] = fmaf(a0, b4.x, acc[0][0]);
        acc[0][1] = fmaf(a0, b4.y, acc[0][1]);
        acc[0][2] = fmaf(a0, b4.z, acc[0][2]);
        acc[0][3] = fmaf(a0, b4.w, acc[0][3]);
        acc[1][0] = fmaf(a1, b4.x, acc[1][0]);
        acc[1][1] = fmaf(a1, b4.y, acc[1][1]);
        acc[1][2] = fmaf(a1, b4.z, acc[1][2]);
        acc[1][3] = fmaf(a1, b4.w, acc[1][3]);
      }
      __syncthreads();
    }
#pragma unroll
    for (int i = 0; i < 2; ++i)
#pragma unroll
      for (int j = 0; j < 4; ++j)
        Ssc[ty * 2 + i][n0 + tx * 4 + j] = acc[i][j];
  }
  __syncthreads();

  // ---- phase 2: full-row softmax, then tril mask (unrenormalized) ----
  {
    const int lane = threadIdx.x & 63, w = threadIdx.x >> 6;  // 4 waves
    for (int r = w; r < AR; r += 4) {
      const int sr = r0 + r;
      float v[8];
      float mx = -INFINITY;
#pragma unroll
      for (int i = 0; i < 8; ++i) {
        v[i] = Ssc[r][lane + i * 64];
        mx = fmaxf(mx, v[i]);
      }
#pragma unroll
      for (int off = 32; off; off >>= 1) mx = fmaxf(mx, __shfl_xor(mx, off));
      float sm = 0.f;
#pragma unroll
      for (int i = 0; i < 8; ++i) { v[i] = expf(v[i] - mx); sm += v[i]; }
#pragma unroll
      for (int off = 32; off; off >>= 1) sm += __shfl_xor(sm, off);
      const float inv = 1.f / sm;
#pragma unroll
      for (int i = 0; i < 8; ++i) {
        int c = lane + i * 64;
        Ssc[r][c] = (c <= sr) ? v[i] * inv : 0.f;
      }
    }
  }
  __syncthreads();

  // ---- phase 3: out rows = Ssc @ h  (M=32, N=512, K=512) ----
  for (int nt = 0; nt < 8; ++nt) {
    const int n0 = nt * 64;
    float acc[2][4] = {};
    for (int k0 = 0; k0 < SS; k0 += 32) {
#pragma unroll
      for (int i = 0; i < 2; ++i) {  // stage Bt = h[k0+kk][n0+n] (NN)
        int f = threadIdx.x + 256 * i;
        int n4 = (f & 15) << 2, kk = f >> 4;
        *(float4*)&Bt[kk][n4] =
            *(const float4*)&h[(size_t)(k0 + kk) * HH + n0 + n4];
      }
      __syncthreads();
#pragma unroll
      for (int kk = 0; kk < 32; ++kk) {
        float a0 = Ssc[ty * 2 + 0][k0 + kk], a1 = Ssc[ty * 2 + 1][k0 + kk];
        float4 b4 = *(const float4*)&Bt[kk][tx * 4];
        acc[0][0] = fmaf(a0, b4.x, acc[0][0]);
        acc[0][1] = fmaf(a0, b4.y, acc[0][1]);
        acc[0][2] = fmaf(a0, b4.z, acc[0][2]);
        acc[0][3] = fmaf(a0, b4.w, acc[0][3]);
        acc[1][0] = fmaf(a1, b4.x, acc[1][0]);
        acc[1][1] = fmaf(a1, b4.y, acc[1][1]);
        acc[1][2] = fmaf(a1, b4.z, acc[1][2]);
        acc[1][3] = fmaf(a1, b4.w, acc[1][3]);
      }
      __syncthreads();
    }
#pragma unroll
    for (int i = 0; i < 2; ++i) {
      float4 o = {acc[i][0], acc[i][1], acc[i][2], acc[i][3]};
      *(float4*)&out[((size_t)b * SS + r0 + ty * 2 + i) * HH + n0 + tx * 4] = o;
    }
  }
}

// ---------------------------------------------------------------------------
extern "C" void kernel_launch(void* const* d_in, const int* in_sizes, int n_in,
                              void* d_out, int out_size, void* d_ws, size_t ws_size,
                              hipStream_t stream) {
  const float* inp  = (const float*)d_in[0];
  // d_in[1] = seq_lens (all == S) — unused
  const float* W_ih = (const float*)d_in[2];
  const float* W_hh = (const float*)d_in[3];
  const float* b_ih = (const float*)d_in[4];
  const float* b_hh = (const float*)d_in[5];
  float* out = (float*)d_out;
  float* ws  = (float*)d_ws;

  // d_ws holds ONLY h_all: 64 * 512 * 512 floats = 64 MiB.
  if (ws_size < (size_t)BB * SS * HH * sizeof(float)) return;  // can't run safely
  float* h_all = ws;

  // d_out doubles as scratch until attn_fused rewrites it.
  float* WihT = out + OUT_OFF_WIHT;
  float* WhhT = out + OUT_OFF_WHHT;
  float* xc   = out + OUT_OFF_XC;

  // 1) transpose weights into d_out scratch
  transpose_k<<<dim3(256 / 32, 1536 / 32), dim3(32, 8), 0, stream>>>(W_ih, WihT, 1536, 256);
  transpose_k<<<dim3(512 / 32, 1536 / 32), dim3(32, 8), 0, stream>>>(W_hh, WhhT, 1536, 512);

  // 2) alternate x_proj chunk GEMM and GRU scan over 4 time chunks
  for (int c = 0; c < NCHUNK; ++c) {
    const int s0 = c * SC;
    xproj_gemm<<<dim3(GG / 64, SC), 256, 0, stream>>>(inp, WihT, b_ih, xc, s0);
    gru_scan_chunk<<<dim3(BB), dim3(512), 0, stream>>>(xc, WhhT, b_hh, h_all, s0);
  }

  // 3) fused attention: gram -> softmax -> tril -> PV, writes all of d_out
  attn_fused<<<dim3(SS / AR, BB), 256, 0, stream>>>(h_all, out);
}